// Round 7
// baseline (46.953 us; speedup 1.0000x reference)
//
#include <hip/hip_runtime.h>
#include <stdint.h>

// AeTransformer_44839458570443: 3-NN inverse-distance interpolation + (tanh+1)/2.
// xyz1: [B,3,N] fp32, xyz2: [B,3,S] fp32, points2: [B,1,S] fp32 -> out [B,N] fp32.
//
// Selection bit-matches the reference fp32 expanded distance
//   d = (-2*((x*x'+y*y')+z*z') + ||q||^2) + ||p||^2   (fp32, no FMA)
// ordered by (d, index).
// Q=4 register blocking: each thread owns 4 consecutive queries so every LDS
// candidate read is reused 4x (R6 was LDS-pipe-bound at ~39us).
// PHASE A (proxy): 64 groups of 8; FMA distances + min-tree -> group min;
//   keep 5 smallest group keys (group id in low 6 mantissa bits).
//   Lemma: at most 3 groups can have min <= d3 -> top-3 lives in best-3
//   groups; 5 kept for proxy/quantization margin.
// PHASE C: exact replicated ref_d over the 40 survivors, quantized 6-slot
//   screen + exact (d,idx) refine + replicated fp32 weight chain (r2-r6).
static constexpr int B = 4;
static constexpr int N = 65536;
static constexpr int S = 512;

// Pack per-sample constants: (x, y, z, ((x*x + y*y) + z*z)) with IEEE fp32 ops
__global__ __launch_bounds__(256) void prep_kernel(const float* __restrict__ xyz2,
                                                   float4* __restrict__ ws) {
    int t = blockIdx.x * 256 + threadIdx.x;
    if (t >= B * S) return;
    int b = t >> 9, s = t & 511;
    const float* p = xyz2 + (size_t)b * 3 * S;
    float x = p[s], y = p[s + S], z = p[s + 2 * S];
    float c = __fadd_rn(__fadd_rn(__fmul_rn(x, x), __fmul_rn(y, y)), __fmul_rn(z, z));
    ws[t] = make_float4(x, y, z, c);
}

// Reference-replicated fp32 distance (numpy order, no contraction)
__device__ __forceinline__ float ref_d(float x1, float y1, float z1, float ssrc, float4 p) {
    float dot = __fadd_rn(__fadd_rn(__fmul_rn(x1, p.x), __fmul_rn(y1, p.y)),
                          __fmul_rn(z1, p.z));
    float t = __fmul_rn(dot, -2.0f);
    return __fadd_rn(__fadd_rn(t, ssrc), p.w);
}

// compare-and-swap on (d, idx) ascending, idx ascending on exact float ties
#define CAS(da_, ia_, db_, ib_)                                     \
    {                                                               \
        bool sw_ = (db_ < da_) || ((db_ == da_) && (ib_ < ia_));    \
        float tda_ = sw_ ? db_ : da_;                               \
        int tia_ = sw_ ? ib_ : ia_;                                 \
        db_ = sw_ ? da_ : db_;                                      \
        ib_ = sw_ ? ia_ : ib_;                                      \
        da_ = tda_;                                                 \
        ia_ = tia_;                                                 \
    }

// branchless sorted insert of key k into ascending 5-list a0..a4
#define INS5(a0, a1, a2, a3, a4, k)                                 \
    {                                                               \
        float t4 = __builtin_amdgcn_fmed3f(a3, (k), a4);            \
        float t3 = __builtin_amdgcn_fmed3f(a2, (k), a3);            \
        float t2 = __builtin_amdgcn_fmed3f(a1, (k), a2);            \
        float t1 = __builtin_amdgcn_fmed3f(a0, (k), a1);            \
        a0 = fminf(a0, (k));                                        \
        a1 = t1; a2 = t2; a3 = t3; a4 = t4;                         \
    }

// branchless sorted insert of key k into ascending 6-list m0..m5
#define INS6(k)                                                     \
    {                                                               \
        float t5 = __builtin_amdgcn_fmed3f(m4, (k), m5);            \
        float t4 = __builtin_amdgcn_fmed3f(m3, (k), m4);            \
        float t3 = __builtin_amdgcn_fmed3f(m2, (k), m3);            \
        float t2 = __builtin_amdgcn_fmed3f(m1, (k), m2);            \
        float t1 = __builtin_amdgcn_fmed3f(m0, (k), m1);            \
        m0 = fminf(m0, (k));                                        \
        m1 = t1; m2 = t2; m3 = t3; m4 = t4; m5 = t5;                \
    }

__global__ __launch_bounds__(256) void knn3_kernel(const float* __restrict__ xyz1,
                                                   const float* __restrict__ points2,
                                                   const float4* __restrict__ ws,
                                                   float* __restrict__ out) {
    __shared__ float4 tile[S];  // 8 KB candidate table
    const int tid = threadIdx.x;
    const int b = blockIdx.x >> 6;                 // 64 blocks per batch
    const int n0 = ((blockIdx.x & 63) << 10) + (tid << 2);  // 4 queries/thread

    const float4* __restrict__ wsrc = ws + b * S;
    tile[tid] = wsrc[tid];
    tile[tid + 256] = wsrc[tid + 256];
    __syncthreads();

    // Load 4 consecutive queries per thread (float4-vectorized)
    const float* q = xyz1 + (size_t)b * 3 * N;
    float4 xq = *(const float4*)(q + n0);
    float4 yq = *(const float4*)(q + N + n0);
    float4 zq = *(const float4*)(q + 2 * N + n0);
    float x1[4] = {xq.x, xq.y, xq.z, xq.w};
    float y1[4] = {yq.x, yq.y, yq.z, yq.w};
    float z1[4] = {zq.x, zq.y, zq.z, zq.w};
    float ssrc[4], c[4], nx2[4], ny2[4], nz2[4];
#pragma unroll
    for (int qi = 0; qi < 4; ++qi) {
        ssrc[qi] = __fadd_rn(__fadd_rn(__fmul_rn(x1[qi], x1[qi]), __fmul_rn(y1[qi], y1[qi])),
                             __fmul_rn(z1[qi], z1[qi]));
        c[qi] = ssrc[qi] + 0.25f;  // screen-only bias keeps packed keys > 0
        nx2[qi] = -2.0f * x1[qi];
        ny2[qi] = -2.0f * y1[qi];
        nz2[qi] = -2.0f * z1[qi];
    }

    // ---- Phase A: group scan; per query keep 5 best (group-min | gid) ----
    float gk[4][5];
#pragma unroll
    for (int qi = 0; qi < 4; ++qi)
#pragma unroll
        for (int j = 0; j < 5; ++j) gk[qi][j] = 3.0e38f;

#pragma unroll 2
    for (int g = 0; g < 64; ++g) {
        float4 p[8];
#pragma unroll
        for (int j = 0; j < 8; ++j) p[j] = tile[g * 8 + j];  // broadcast reads
#pragma unroll
        for (int qi = 0; qi < 4; ++qi) {
            float e[8];
#pragma unroll
            for (int j = 0; j < 8; ++j)
                e[j] = fmaf(nx2[qi], p[j].x,
                            fmaf(ny2[qi], p[j].y, fmaf(nz2[qi], p[j].z, p[j].w)));
            // min tree (8 -> 1): nested fminf fuses to v_min3_f32
            float mA = fminf(fminf(e[0], e[1]), e[2]);
            float mB = fminf(fminf(e[3], e[4]), e[5]);
            float mC = fminf(fminf(mA, mB), e[6]);
            float gm = fminf(mC, e[7]);
            float gkey = __uint_as_float((__float_as_uint(gm + c[qi]) & 0xFFFFFFC0u) |
                                         (uint32_t)g);
            INS5(gk[qi][0], gk[qi][1], gk[qi][2], gk[qi][3], gk[qi][4], gkey);
        }
    }

    // ---- Phase C + refine + epilogue, per query ----
    float res[4];
    const float* f = points2 + (size_t)b * S;  // D = 1
#pragma unroll
    for (int qi = 0; qi < 4; ++qi) {
        float m0 = 3.0e38f, m1 = 3.0e38f, m2 = 3.0e38f,
              m3 = 3.0e38f, m4 = 3.0e38f, m5 = 3.0e38f;
#pragma unroll
        for (int t = 0; t < 5; ++t) {
            int gbase = (int)(__float_as_uint(gk[qi][t]) & 63u) << 3;
#pragma unroll
            for (int j = 0; j < 8; ++j) {
                float4 p = tile[gbase + j];  // divergent LDS gather
                float d = ref_d(x1[qi], y1[qi], z1[qi], ssrc[qi], p);
                float e2 = __fadd_rn(d, 0.25f);
                float k = __uint_as_float((__float_as_uint(e2) & 0xFFFFFE00u) |
                                          (uint32_t)(gbase + j));
                INS6(k);
            }
        }

        int gi[6];
        float dd[6];
        gi[0] = (int)(__float_as_uint(m0) & 511u);
        gi[1] = (int)(__float_as_uint(m1) & 511u);
        gi[2] = (int)(__float_as_uint(m2) & 511u);
        gi[3] = (int)(__float_as_uint(m3) & 511u);
        gi[4] = (int)(__float_as_uint(m4) & 511u);
        gi[5] = (int)(__float_as_uint(m5) & 511u);
#pragma unroll
        for (int j = 0; j < 6; ++j)
            dd[j] = ref_d(x1[qi], y1[qi], z1[qi], ssrc[qi], tile[gi[j]]);

#pragma unroll
        for (int pp = 0; pp < 3; ++pp)
#pragma unroll
            for (int i = 4; i >= pp; --i) CAS(dd[i], gi[i], dd[i + 1], gi[i + 1]);

        // Replicate reference weight/interp chain in fp32, nearest-first order
        const float EPS32 = 1e-8f;
        float r0 = __fdiv_rn(1.0f, __fadd_rn(dd[0], EPS32));
        float r1 = __fdiv_rn(1.0f, __fadd_rn(dd[1], EPS32));
        float r2 = __fdiv_rn(1.0f, __fadd_rn(dd[2], EPS32));
        float rs = __fadd_rn(__fadd_rn(r0, r1), r2);
        float w0 = __fdiv_rn(r0, rs);
        float w1 = __fdiv_rn(r1, rs);
        float w2 = __fdiv_rn(r2, rs);
        float interp = __fadd_rn(__fadd_rn(__fmul_rn(f[gi[0]], w0), __fmul_rn(f[gi[1]], w1)),
                                 __fmul_rn(f[gi[2]], w2));
        float t = tanhf(interp);
        res[qi] = __fmul_rn(__fadd_rn(t, 1.0f), 0.5f);
    }

    *(float4*)(out + ((size_t)b << 16) + n0) = make_float4(res[0], res[1], res[2], res[3]);
}

extern "C" void kernel_launch(void* const* d_in, const int* in_sizes, int n_in,
                              void* d_out, int out_size, void* d_ws, size_t ws_size,
                              hipStream_t stream) {
    const float* xyz1 = (const float*)d_in[0];
    const float* xyz2 = (const float*)d_in[1];
    const float* points2 = (const float*)d_in[2];
    float* out = (float*)d_out;
    float4* ws = (float4*)d_ws;  // B*S*16 = 32 KB

    prep_kernel<<<(B * S + 255) / 256, 256, 0, stream>>>(xyz2, ws);
    // 256 blocks x 256 threads, 4 queries/thread
    knn3_kernel<<<(B * N) / 1024, 256, 0, stream>>>(xyz1, points2, ws, out);
}